// Round 5
// baseline (678.952 us; speedup 1.0000x reference)
//
#include <hip/hip_runtime.h>
#include <hip/hip_bf16.h>
#include <math.h>

// ---------------------------------------------------------------------------
// ToyMoE: top-1 routed 2-expert MLP. H=2048, tokens = 8192.
//   R2: 770us. BK=32 2-barrier: GEMMs 2x243us, conflicts 1.7e7.
//   R3: 680us. BK=64: 2x228us, conflicts 5.1e7 (128B row stride, 8-way).
//   R4: 604us. XOR swizzle: 2x191us, conflicts 0. Mfma 32 + VALU 23 ->
//       45% stall = vmcnt(0) drain right after issuing stage (no overlap).
//   R5: BK=32 double-buffered, ONE barrier/iter: stage(next) issued after
//       barrier, drain for it happens at NEXT iter's barrier -> overlapped
//       with full MFMA phase. LDS 2x16KB = 32KB (same occupancy as R4).
//       Gate+cast fused into one dispatch.
// ---------------------------------------------------------------------------

#define HDIM   2048
#define TOKENS 8192
#define FDIM   4096   // 2*H

typedef __bf16 bf16x8 __attribute__((ext_vector_type(8)));
typedef __bf16 bf16x4 __attribute__((ext_vector_type(4)));
typedef float  f32x4  __attribute__((ext_vector_type(4)));

// workspace layout (bytes)
#define CNT_OFF  0           // n0 (int), n1 (int)
#define PERM_OFF 256         // int[8192]
#define XG_OFF   65536       // bf16 [8192][2048]   = 33554432 B
#define WA_OFF   33619968    // bf16 [2][4096][2048] = 33554432 B
#define WB_OFF   67174400    // bf16 [2][2048][4096] = 33554432 B
#define HB_OFF   100728832   // bf16 [8192][4096]    = 67108864 B

typedef __attribute__((address_space(1))) const unsigned int as1_u32;
typedef __attribute__((address_space(3))) unsigned int       as3_u32;

__device__ __forceinline__ void gl2lds16(const void* g, void* l) {
    __builtin_amdgcn_global_load_lds((as1_u32*)g, (as3_u32*)l, 16, 0, 0);
}

// ------- fused prep: gate (fp64 argmax + routed gather) & weight cast ------
// blocks [0,2048): gate+gather, 4 tokens/block (1 per wave).
// blocks [2048,18432): cast one of 4 weight matrices to bf16.
__global__ void moe_prep(const float* __restrict__ x, const float* __restrict__ Wg,
                         const float* __restrict__ W0a, const float* __restrict__ W1a,
                         const float* __restrict__ W0b, const float* __restrict__ W1b,
                         int* __restrict__ n0, int* __restrict__ n1,
                         int* __restrict__ perm, __bf16* __restrict__ Xg,
                         __bf16* __restrict__ Wa, __bf16* __restrict__ Wb) {
    const int tid  = threadIdx.x;
    if (blockIdx.x >= 2048) {
        // ---- weight cast path ----
        const int cb    = blockIdx.x - 2048;
        const int slice = cb >> 12;          // 0..3
        const int bx    = cb & 4095;
        const float* src;
        __bf16* dst;
        const size_t MS = (size_t)FDIM * HDIM;
        if      (slice == 0) { src = W0a; dst = Wa; }
        else if (slice == 1) { src = W1a; dst = Wa + MS; }
        else if (slice == 2) { src = W0b; dst = Wb; }
        else                 { src = W1b; dst = Wb + MS; }
        const size_t idx = ((size_t)bx * 256 + tid) * 8;
        float4 a = *reinterpret_cast<const float4*>(src + idx);
        float4 b = *reinterpret_cast<const float4*>(src + idx + 4);
        bf16x8 v;
        v[0] = (__bf16)a.x; v[1] = (__bf16)a.y; v[2] = (__bf16)a.z; v[3] = (__bf16)a.w;
        v[4] = (__bf16)b.x; v[5] = (__bf16)b.y; v[6] = (__bf16)b.z; v[7] = (__bf16)b.w;
        *reinterpret_cast<bf16x8*>(dst + idx) = v;
        return;
    }
    // ---- gate + gather path ----
    __shared__ int sel[4];
    __shared__ int pos[4];
    const int wid  = tid >> 6;
    const int lane = tid & 63;
    const int token = blockIdx.x * 4 + wid;
    const float* xr = x + (size_t)token * HDIM;

    float4 xv[8];
    double s0 = 0.0, s1 = 0.0;
#pragma unroll
    for (int j = 0; j < 8; j++) {
        const int idx = j * 256 + lane * 4;
        xv[j] = *reinterpret_cast<const float4*>(xr + idx);
        float4 g0 = *reinterpret_cast<const float4*>(Wg + idx);
        float4 g1 = *reinterpret_cast<const float4*>(Wg + HDIM + idx);
        s0 += (double)xv[j].x * g0.x + (double)xv[j].y * g0.y
            + (double)xv[j].z * g0.z + (double)xv[j].w * g0.w;
        s1 += (double)xv[j].x * g1.x + (double)xv[j].y * g1.y
            + (double)xv[j].z * g1.z + (double)xv[j].w * g1.w;
    }
#pragma unroll
    for (int off = 32; off > 0; off >>= 1) {
        s0 += __shfl_down(s0, off);
        s1 += __shfl_down(s1, off);
    }
    if (lane == 0) sel[wid] = (s1 > s0) ? 1 : 0;   // softmax monotone; ties -> e0
    __syncthreads();
    if (tid == 0) {
        int c0 = (sel[0] == 0) + (sel[1] == 0) + (sel[2] == 0) + (sel[3] == 0);
        int p0 = c0 ? atomicAdd(n0, c0) : 0;
        int p1 = (c0 < 4) ? atomicAdd(n1, 4 - c0) : 0;
#pragma unroll
        for (int w = 0; w < 4; w++) {
            if (sel[w] == 0) pos[w] = p0++;
            else             pos[w] = TOKENS - 1 - (p1++);
        }
    }
    __syncthreads();
    const int dst = pos[wid];
    if (lane == 0) perm[dst] = token;
    __bf16* dr = Xg + (size_t)dst * HDIM;
#pragma unroll
    for (int j = 0; j < 8; j++) {
        const int idx = j * 256 + lane * 4;
        bf16x4 v;
        v[0] = (__bf16)xv[j].x; v[1] = (__bf16)xv[j].y;
        v[2] = (__bf16)xv[j].z; v[3] = (__bf16)xv[j].w;
        *reinterpret_cast<bf16x4*>(dr + idx) = v;
    }
}

// ------- MFMA GEMM, 128x128 tile, BK=32, double-buffered LDS, swizzled -----
// A:[8192][KDIM] bf16, Bw:[2][NDIM][KDIM] bf16 (K-contiguous, B^T GEMM)
// LDS slot (row r, 16B-chunk c') holds global chunk c' ^ ((r>>1)&3).
// One barrier per K-iter; stage(next buf) issued right after the barrier so
// its vmcnt drain (at the NEXT barrier) overlaps this iter's MFMAs.
template <int KDIM, int NDIM, bool DOWN>
__global__ void moe_gemm(const __bf16* __restrict__ A, const __bf16* __restrict__ Bw,
                         const float* __restrict__ bias0, const float* __restrict__ bias1,
                         __bf16* __restrict__ Hb, float* __restrict__ Out,
                         const int* __restrict__ n0_ptr, const int* __restrict__ perm) {
    const int e  = blockIdx.z;
    const int n0 = *n0_ptr;
    const int row_lo = e ? n0 : 0;
    const int row_hi = e ? TOKENS : n0;
    const int bm = blockIdx.y * 128;
    if (bm >= row_hi || bm + 128 <= row_lo) return;
    const int bn = blockIdx.x * 128;

    __shared__ __bf16 As[2][128 * 32];   // 2 x 8 KB
    __shared__ __bf16 Bs[2][128 * 32];   // 2 x 8 KB

    const int tid  = threadIdx.x;
    const int wid  = tid >> 6;
    const int lane = tid & 63;

    const __bf16* Be   = Bw + (size_t)e * NDIM * KDIM;
    const float*  bias = e ? bias1 : bias0;

    // staging: one gl2lds16 = 16 rows x 64B. lane l -> row l>>2, slot chunk
    // l&3; swizzled source chunk (l&3)^((l>>3)&3). Wave stages 32 rows (2 calls).
    const int lr  = lane >> 2;
    const int ssw = (((lane & 3) ^ ((lane >> 3) & 3)) * 8);
    const __bf16* gA0 = A  + (size_t)(bm + wid * 32 + lr) * KDIM + ssw;
    const __bf16* gA1 = gA0 + (size_t)16 * KDIM;
    const __bf16* gB0 = Be + (size_t)(bn + wid * 32 + lr) * KDIM + ssw;
    const __bf16* gB1 = gB0 + (size_t)16 * KDIM;
    const int lbase0 = (wid * 32) * 32;
    const int lbase1 = (wid * 32 + 16) * 32;

    const int wrow = (wid >> 1) * 64;
    const int wcol = (wid & 1) * 64;
    const int rm = lane & 15;
    const int g  = lane >> 4;                    // 0..3
    const int csw = ((g ^ ((rm >> 1) & 3)) * 8); // read-side swizzled chunk

    f32x4 acc[4][4] = {};

    // prologue: stage kt=0 into buf 0
    gl2lds16(gA0, &As[0][lbase0]);
    gl2lds16(gA1, &As[0][lbase1]);
    gl2lds16(gB0, &Bs[0][lbase0]);
    gl2lds16(gB1, &Bs[0][lbase1]);

    int p = 0;
    for (int kt = 0; kt < KDIM; kt += 32) {
        __syncthreads();   // buf p staged (vmcnt drain overlapped w/ prev MFMAs)
        if (kt + 32 < KDIM) {
            const int q = p ^ 1;
            gl2lds16(gA0 + kt + 32, &As[q][lbase0]);
            gl2lds16(gA1 + kt + 32, &As[q][lbase1]);
            gl2lds16(gB0 + kt + 32, &Bs[q][lbase0]);
            gl2lds16(gB1 + kt + 32, &Bs[q][lbase1]);
        }
        bf16x8 aF[4], bF[4];
#pragma unroll
        for (int i = 0; i < 4; i++) {
            aF[i] = *reinterpret_cast<const bf16x8*>(&As[p][(wrow + i * 16 + rm) * 32 + csw]);
            bF[i] = *reinterpret_cast<const bf16x8*>(&Bs[p][(wcol + i * 16 + rm) * 32 + csw]);
        }
#pragma unroll
        for (int i = 0; i < 4; i++)
#pragma unroll
            for (int j = 0; j < 4; j++)
                acc[i][j] = __builtin_amdgcn_mfma_f32_16x16x32_bf16(aF[i], bF[j], acc[i][j], 0, 0, 0);
        p ^= 1;
    }

    // epilogue. C/D layout: col = lane&15, row = (lane>>4)*4 + reg  [m89/m91]
    const int q4 = g * 4;
#pragma unroll
    for (int j = 0; j < 4; j++) {
        const int col = bn + wcol + j * 16 + rm;
        const float bv = bias[col];
#pragma unroll
        for (int i = 0; i < 4; i++) {
            const int rbase = bm + wrow + i * 16 + q4;
#pragma unroll
            for (int r = 0; r < 4; r++) {
                const int row = rbase + r;
                if (row >= row_lo && row < row_hi) {
                    float v = acc[i][j][r] + bv;
                    if (!DOWN) {
                        if (e == 0) v = 0.5f * v * (1.0f + erff(v * 0.70710678118654752f));
                        else        v = v > 0.0f ? v : 0.0f;
                        Hb[(size_t)row * NDIM + col] = (__bf16)v;
                    } else {
                        Out[(size_t)perm[row] * HDIM + col] = v;
                    }
                }
            }
        }
    }
}

extern "C" void kernel_launch(void* const* d_in, const int* in_sizes, int n_in,
                              void* d_out, int out_size, void* d_ws, size_t ws_size,
                              hipStream_t stream) {
    const float* x   = (const float*)d_in[0];
    const float* Wg  = (const float*)d_in[1];
    const float* W0a = (const float*)d_in[2];
    const float* b0a = (const float*)d_in[3];
    const float* W0b = (const float*)d_in[4];
    const float* b0b = (const float*)d_in[5];
    const float* W1a = (const float*)d_in[6];
    const float* b1a = (const float*)d_in[7];
    const float* W1b = (const float*)d_in[8];
    const float* b1b = (const float*)d_in[9];
    float* out = (float*)d_out;

    char* w = (char*)d_ws;
    int* n0   = (int*)(w + CNT_OFF);
    int* n1   = n0 + 1;
    int* perm = (int*)(w + PERM_OFF);
    __bf16* Xg = (__bf16*)(w + XG_OFF);
    __bf16* Wa = (__bf16*)(w + WA_OFF);
    __bf16* Wb = (__bf16*)(w + WB_OFF);
    __bf16* Hb = (__bf16*)(w + HB_OFF);

    (void)hipMemsetAsync(w, 0, 256, stream);
    moe_prep<<<2048 + 16384, 256, 0, stream>>>(x, Wg, W0a, W1a, W0b, W1b,
                                               n0, n1, perm, Xg, Wa, Wb);
    moe_gemm<HDIM, FDIM, false><<<dim3(FDIM / 128, TOKENS / 128, 2), 256, 0, stream>>>(
        Xg, Wa, b0a, b1a, Hb, nullptr, n0, perm);
    moe_gemm<FDIM, HDIM, true><<<dim3(HDIM / 128, TOKENS / 128, 2), 256, 0, stream>>>(
        Hb, Wb, b0b, b1b, nullptr, out, n0, perm);
}